// Round 5
// baseline (181.614 us; speedup 1.0000x reference)
//
#include <hip/hip_runtime.h>
#include <stdint.h>

#define SEQ 2048
#define NH  16

typedef __bf16 bf16x8 __attribute__((ext_vector_type(8)));
typedef float  f32x4  __attribute__((ext_vector_type(4)));
typedef float  f32x16 __attribute__((ext_vector_type(16)));
typedef unsigned uint2v __attribute__((ext_vector_type(2)));

#if __has_builtin(__builtin_amdgcn_exp2f)
#define EXP2(x) __builtin_amdgcn_exp2f(x)
#else
#define EXP2(x) exp2f(x)
#endif

#define WAITV0 asm volatile("s_waitcnt vmcnt(0)" ::: "memory")
#define WAITV4 asm volatile("s_waitcnt vmcnt(4)" ::: "memory")
#define SBAR() do { __builtin_amdgcn_sched_barrier(0); __builtin_amdgcn_s_barrier(); __builtin_amdgcn_sched_barrier(0); } while (0)

__device__ __forceinline__ void gll16(const void* g, void* l) {
  __builtin_amdgcn_global_load_lds((const __attribute__((address_space(1))) void*)g,
                                   (__attribute__((address_space(3))) void*)l, 16, 0, 0);
}

__device__ __forceinline__ f32x4 mfma16(bf16x8 a, bf16x8 b, f32x4 c) {
  return __builtin_amdgcn_mfma_f32_16x16x32_bf16(a, b, c, 0, 0, 0);
}
__device__ __forceinline__ f32x16 mfma32(bf16x8 a, bf16x8 b, f32x16 c) {
  return __builtin_amdgcn_mfma_f32_32x32x16_bf16(a, b, c, 0, 0, 0);
}

// ---------------- GEMM BMx128, BK=64, single-buffered; fp32 inputs staged in-kernel ---
// C[m][n] = (sum_k A[m][k]*W[n][k] + bias[n]) * scale
// mode 0: bf16 [B,H,S,DK]; mode 1: bf16 [B,H,DK,S]; mode 2: fp32 [M][N].
struct GemmJobs {
  const void* A[3];        // fp32 (AFP32) or bf16
  const float* W[3];       // fp32 always
  const float* bias[3];
  void* out[3];
  float scale[3];
  int mode[3];
};

template<int BM, int NB, bool AFP32>
__global__ __launch_bounds__(256, (BM == 128 ? 3 : 2)) void gemm_t(GemmJobs J) {
  __shared__ alignas(16) unsigned short Asm[BM * 64];
  __shared__ alignas(16) unsigned short Bsm[128 * 64];
  constexpr int MFR = BM / 32;    // acc row-frags per wave
  constexpr int MB = 4096 / BM;   // m-blocks per job
  const int tid = threadIdx.x;
  const int l = tid & 63, w = tid >> 6;
  const int wr = w >> 1, wc = w & 1;
  const int lg = l >> 4, lo = l & 15;

  // XCD-aware swizzle (nwg % 8 == 0)
  const int nwg = gridDim.x;
  const int id = blockIdx.x;
  const int swz = (id & 7) * (nwg >> 3) + (id >> 3);
  const int g = swz / NB;
  const int rem = swz % NB;
  const int m0 = (rem % MB) * BM;     // m fastest: consecutive blocks share W panel
  const int n0 = (rem / MB) * 128;

  const float* __restrict__ W = J.W[g];
  const float* __restrict__ bias = J.bias[g];
  const int mode = J.mode[g];
  const float scale = J.scale[g];

  f32x4 acc[MFR][4] = {};

  for (int kt = 0; kt < 16; ++kt) {
    // ---- stage A tile (BM x 64 k) ----
    if constexpr (AFP32) {
      const float* __restrict__ A = (const float*)J.A[g];
#pragma unroll
      for (int it = 0; it < BM / 32; ++it) {
        int g8 = it * 256 + tid;
        int row = g8 >> 3, c = g8 & 7;
        const float* src = A + (((size_t)(m0 + row)) << 10) + (kt << 6) + c * 8;
        float4 u0 = ((const float4*)src)[0];
        float4 u1 = ((const float4*)src)[1];
        union { __bf16 b[8]; bf16x8 v; } cv;
        cv.b[0] = (__bf16)u0.x; cv.b[1] = (__bf16)u0.y; cv.b[2] = (__bf16)u0.z; cv.b[3] = (__bf16)u0.w;
        cv.b[4] = (__bf16)u1.x; cv.b[5] = (__bf16)u1.y; cv.b[6] = (__bf16)u1.z; cv.b[7] = (__bf16)u1.w;
        *(bf16x8*)((char*)Asm + row * 128 + ((c ^ (row & 7)) << 4)) = cv.v;
      }
    } else {
      const unsigned short* __restrict__ A = (const unsigned short*)J.A[g];
#pragma unroll
      for (int it = 0; it < BM / 32; ++it) {
        int chunk = it * 256 + tid;
        int row = chunk >> 3, c = chunk & 7;
        const char* src = (const char*)A + (((size_t)(m0 + row) << 10) + (kt << 6)) * 2 + ((c ^ (row & 7)) << 4);
        gll16(src, (char*)Asm + ((it * 256 + (tid & ~63)) << 4));
      }
    }
    // ---- stage W tile (128 rows x 64 k), fp32 ----
#pragma unroll
    for (int it = 0; it < 4; ++it) {
      int g8 = it * 256 + tid;
      int row = g8 >> 3, c = g8 & 7;
      const float* src = W + (((size_t)(n0 + row)) << 10) + (kt << 6) + c * 8;
      float4 u0 = ((const float4*)src)[0];
      float4 u1 = ((const float4*)src)[1];
      union { __bf16 b[8]; bf16x8 v; } cv;
      cv.b[0] = (__bf16)u0.x; cv.b[1] = (__bf16)u0.y; cv.b[2] = (__bf16)u0.z; cv.b[3] = (__bf16)u0.w;
      cv.b[4] = (__bf16)u1.x; cv.b[5] = (__bf16)u1.y; cv.b[6] = (__bf16)u1.z; cv.b[7] = (__bf16)u1.w;
      *(bf16x8*)((char*)Bsm + row * 128 + ((c ^ (row & 7)) << 4)) = cv.v;
    }
    if constexpr (!AFP32) { WAITV0; }
    __syncthreads();
#pragma unroll
    for (int kf = 0; kf < 2; ++kf) {
      bf16x8 af[MFR], bfr[4];
#pragma unroll
      for (int mf = 0; mf < MFR; ++mf) {
        int row = wr * (BM / 2) + mf * 16 + lo;
        int pos = (kf * 4 + lg) ^ (row & 7);
        af[mf] = *(const bf16x8*)((const char*)Asm + row * 128 + pos * 16);
      }
#pragma unroll
      for (int nf = 0; nf < 4; ++nf) {
        int row = wc * 64 + nf * 16 + lo;
        int pos = (kf * 4 + lg) ^ (row & 7);
        bfr[nf] = *(const bf16x8*)((const char*)Bsm + row * 128 + pos * 16);
      }
#pragma unroll
      for (int mf = 0; mf < MFR; ++mf)
#pragma unroll
        for (int nf = 0; nf < 4; ++nf)
          acc[mf][nf] = mfma16(af[mf], bfr[nf], acc[mf][nf]);
    }
    __syncthreads();  // all waves done reading before restage
  }

  // epilogue
#pragma unroll
  for (int mf = 0; mf < MFR; ++mf)
#pragma unroll
    for (int nf = 0; nf < 4; ++nf) {
      int gcol = n0 + wc * 64 + nf * 16 + lo;
      float bv = bias[gcol];
#pragma unroll
      for (int r = 0; r < 4; ++r) {
        int grow = m0 + wr * (BM / 2) + mf * 16 + lg * 4 + r;
        float v = (acc[mf][nf][r] + bv) * scale;
        if (mode == 2) {
          ((float*)J.out[g])[((size_t)grow << 10) + gcol] = v;
        } else {
          int b = grow >> 11, s = grow & 2047, h = gcol >> 6, dk = gcol & 63;
          size_t idx;
          if (mode == 0) idx = ((((size_t)((b << 4) + h) << 11) + s) << 6) + dk;
          else           idx = ((((size_t)((b << 4) + h) << 6) + dk) << 11) + s;
          ((__bf16*)J.out[g])[idx] = (__bf16)v;
        }
      }
    }
}

// ---------------- flash attention: 32x32 MFMA, in-register softmax (T12) -------------
// Qb: [B*H][S][64] bf16. Kb: same, pre-scaled by 0.125*log2(e). Vt: [B*H][64][S] bf16.
// Grid 512 (XCD-swizzled -> bh, qtile), 256 threads = 4 waves x 32 q-rows. KVBLK=64 dbuf.
// Per lane: ql = l&31 (owns softmax of q=ql), hi = l>>5.
// QK^T swapped: sN[reg] = S[kv = N*32 + (reg&3)+8*(reg>>2)+4*hi][q = ql].
__global__ __launch_bounds__(256, 2) void attn_kernel(const unsigned short* __restrict__ Qb,
                                                      const unsigned short* __restrict__ Kb,
                                                      const unsigned short* __restrict__ Vt,
                                                      unsigned short* __restrict__ ctx) {
  __shared__ alignas(16) unsigned short Ksm[2][64 * 64];  // [kv][64dk] swizzled, dbuf (16KB)
  __shared__ alignas(16) unsigned short Vsm[2][64 * 64];  // [dk][64kv] swizzled, dbuf (16KB)
  const int tid = threadIdx.x;
  const int l = tid & 63, w = tid >> 6;   // 4 waves
  const int ql = l & 31, hi = l >> 5;

  // XCD swizzle: 512 blocks -> each XCD owns 4 complete heads
  const int id = blockIdx.x;
  const int swz = (id & 7) * 64 + (id >> 3);
  const int bh = swz >> 4;
  const int qt = swz & 15;

  const unsigned short* Qp = Qb + (size_t)bh * SEQ * 64;
  const unsigned short* Kp = Kb + (size_t)bh * SEQ * 64;
  const unsigned short* Vp = Vt + (size_t)bh * 64 * SEQ;
  const int q0 = qt * 128 + w * 32;

  // Q as B-operand: qb[c] = Q[q0+ql][c*16 + hi*8 .. +7]
  bf16x8 qb[4];
#pragma unroll
  for (int c = 0; c < 4; ++c)
    qb[c] = *(const bf16x8*)((const char*)Qp + (((size_t)(q0 + ql)) << 7) + c * 32 + hi * 16);
  WAITV0;  // Q retired; vmcnt now tracks only staging

  f32x16 o0 = {}, o1 = {};      // O[q(reg)][dk = ql] and [dk = 32+ql]
  float m_ = -1e30f, l_ = 0.f;  // running max/sum for q = ql (dup across hi)

#define ASTAGE(b, t)                                                                      \
  do {                                                                                    \
    const int kv0s = (t) << 6;                                                            \
    _Pragma("unroll")                                                                     \
    for (int it = 0; it < 2; ++it) {                                                      \
      int chunk = it * 256 + tid;                                                         \
      int row = chunk >> 3, c = chunk & 7;                                                \
      const char* ksrc = (const char*)Kp + ((size_t)(kv0s + row) << 7) + ((c ^ (row & 7)) << 4); \
      gll16(ksrc, (char*)Ksm[b] + ((it * 256 + (tid & ~63)) << 4));                       \
      const char* vsrc = (const char*)Vp + ((size_t)row << 12) + (kv0s << 1) + ((c ^ (row & 7)) << 4); \
      gll16(vsrc, (char*)Vsm[b] + ((it * 256 + (tid & ~63)) << 4));                       \
    }                                                                                     \
  } while (0)

  ASTAGE(0, 0);

  for (int t = 0; t < SEQ / 64; ++t) {
    const int cur = t & 1;
    if (t < SEQ / 64 - 1) {
      ASTAGE(cur ^ 1, t + 1);
      WAITV4;          // current tile's 4 loads done; next tile's 4 in flight
    } else {
      WAITV0;
    }
    SBAR();

    // ---- S^T = K Q^T (swapped) ----
    f32x16 s0 = {}, s1 = {};
    __builtin_amdgcn_s_setprio(1);
#pragma unroll
    for (int c = 0; c < 4; ++c) {
      int pr = c * 2 + hi;
      bf16x8 k0 = *(const bf16x8*)((const char*)Ksm[cur] + ql * 128 + ((pr ^ (ql & 7)) << 4));
      bf16x8 k1 = *(const bf16x8*)((const char*)Ksm[cur] + (32 + ql) * 128 + ((pr ^ ((32 + ql) & 7)) << 4));
      s0 = mfma32(k0, qb[c], s0);
      s1 = mfma32(k1, qb[c], s1);
    }
    __builtin_amdgcn_s_setprio(0);

    // ---- online softmax, fully lane-local for q = ql ----
#define MAX4(v, i) fmaxf(fmaxf(v[i], v[i+1]), fmaxf(v[i+2], v[i+3]))
    float mA = fmaxf(fmaxf(MAX4(s0, 0), MAX4(s0, 4)), fmaxf(MAX4(s0, 8), MAX4(s0, 12)));
    float mB = fmaxf(fmaxf(MAX4(s1, 0), MAX4(s1, 4)), fmaxf(MAX4(s1, 8), MAX4(s1, 12)));
    float mx = fmaxf(mA, mB);
    mx = fmaxf(mx, __shfl_xor(mx, 32));
#undef MAX4

    if (__any((int)(mx > m_))) {
      float mnew = fmaxf(m_, mx);
      float fac = EXP2(m_ - mnew);
      m_ = mnew;
#pragma unroll
      for (int r = 0; r < 16; ++r) { s0[r] = EXP2(s0[r] - mnew); s1[r] = EXP2(s1[r] - mnew); }
#define SUM4(v, i) ((v[i] + v[i+1]) + (v[i+2] + v[i+3]))
      float ps = ((SUM4(s0, 0) + SUM4(s0, 4)) + (SUM4(s0, 8) + SUM4(s0, 12)))
               + ((SUM4(s1, 0) + SUM4(s1, 4)) + (SUM4(s1, 8) + SUM4(s1, 12)));
      ps += __shfl_xor(ps, 32);
      l_ = l_ * fac + ps;
      // O-rescale: fac indexed by reg-row q, lives at lane q
#pragma unroll
      for (int reg = 0; reg < 16; ++reg) {
        int qrow = (reg & 3) + 8 * (reg >> 2) + 4 * hi;
        float fb = __shfl(fac, qrow);
        o0[reg] *= fb; o1[reg] *= fb;
      }
    } else {
#pragma unroll
      for (int r = 0; r < 16; ++r) { s0[r] = EXP2(s0[r] - m_); s1[r] = EXP2(s1[r] - m_); }
      float ps = ((SUM4(s0, 0) + SUM4(s0, 4)) + (SUM4(s0, 8) + SUM4(s0, 12)))
               + ((SUM4(s1, 0) + SUM4(s1, 4)) + (SUM4(s1, 8) + SUM4(s1, 12)));
      ps += __shfl_xor(ps, 32);
      l_ += ps;
#undef SUM4
    }

    // ---- P -> A-operand in registers: cvt_pk + permlane32_swap (no LDS) ----
    // pa[c] elem j = P[q=ql][kv = c*16 + hi*8 + j]
    bf16x8 pa[4];
#pragma unroll
    for (int c = 0; c < 4; ++c) {
      const int rb = (c & 1) * 8;
      float e0, e1, e2, e3, e4, e5, e6, e7;
      if ((c >> 1) == 0) { e0=s0[rb]; e1=s0[rb+1]; e2=s0[rb+2]; e3=s0[rb+3]; e4=s0[rb+4]; e5=s0[rb+5]; e6=s0[rb+6]; e7=s0[rb+7]; }
      else               { e0=s1[rb]; e1=s1[rb+1]; e2=s1[rb+2]; e3=s1[rb+3]; e4=s1[rb+4]; e5=s1[rb+5]; e6=s1[rb+6]; e7=s1[rb+7]; }
      unsigned X0, X1, Z0, Z1;
      asm("v_cvt_pk_bf16_f32 %0, %1, %2" : "=v"(X0) : "v"(e0), "v"(e1));
      asm("v_cvt_pk_bf16_f32 %0, %1, %2" : "=v"(X1) : "v"(e2), "v"(e3));
      asm("v_cvt_pk_bf16_f32 %0, %1, %2" : "=v"(Z0) : "v"(e4), "v"(e5));
      asm("v_cvt_pk_bf16_f32 %0, %1, %2" : "=v"(Z1) : "v"(e6), "v"(e7));
      uint2v rA = __builtin_amdgcn_permlane32_swap(X0, Z0, false, false);
      uint2v rB = __builtin_amdgcn_permlane32_swap(X1, Z1, false, false);
      union { unsigned u[4]; bf16x8 v; } pk_;
      pk_.u[0] = rA[0]; pk_.u[1] = rB[0]; pk_.u[2] = rA[1]; pk_.u[3] = rB[1];
      pa[c] = pk_.v;
    }

    // ---- O += P V ----
    __builtin_amdgcn_s_setprio(1);
#pragma unroll
    for (int c = 0; c < 4; ++c) {
      int pr = c * 2 + hi;
      bf16x8 v0 = *(const bf16x8*)((const char*)Vsm[cur] + ql * 128 + ((pr ^ (ql & 7)) << 4));
      bf16x8 v1 = *(const bf16x8*)((const char*)Vsm[cur] + (32 + ql) * 128 + ((pr ^ ((32 + ql) & 7)) << 4));
      o0 = mfma32(pa[c], v0, o0);
      o1 = mfma32(pa[c], v1, o1);
    }
    __builtin_amdgcn_s_setprio(0);
    SBAR();  // all waves done reading buf[cur] before restage
  }
#undef ASTAGE

  // ---- epilogue: normalize, store ctx [B*S][1024] ----
  const int b = bh >> 4, h = bh & 15;
#pragma unroll
  for (int reg = 0; reg < 16; ++reg) {
    int qrow = (reg & 3) + 8 * (reg >> 2) + 4 * hi;
    float lr = __shfl(l_, qrow);
    float inv = 1.f / lr;
    int srow = q0 + qrow;
    size_t off = (((size_t)(b * SEQ + srow)) << 10) + h * 64 + ql;
    ((__bf16*)ctx)[off]      = (__bf16)(o0[reg] * inv);
    ((__bf16*)ctx)[off + 32] = (__bf16)(o1[reg] * inv);
  }
}

// ---------------- launch ----------------
extern "C" void kernel_launch(void* const* d_in, const int* in_sizes, int n_in,
                              void* d_out, int out_size, void* d_ws, size_t ws_size,
                              hipStream_t stream) {
  const float* query = (const float*)d_in[0];
  const float* key_  = (const float*)d_in[1];
  const float* value = (const float*)d_in[2];
  const float* wq = (const float*)d_in[4];
  const float* bq = (const float*)d_in[5];
  const float* wk = (const float*)d_in[6];
  const float* bk = (const float*)d_in[7];
  const float* wv = (const float*)d_in[8];
  const float* bv = (const float*)d_in[9];
  const float* wo = (const float*)d_in[10];
  const float* bo = (const float*)d_in[11];

  char* ws = (char*)d_ws;
  unsigned short* Qb  = (unsigned short*)(ws + 0);          // [B,H,S,64] bf16, 8MB
  unsigned short* Kb  = (unsigned short*)(ws + 8388608);    // [B,H,S,64] bf16 (pre-scaled)
  unsigned short* Vb  = (unsigned short*)(ws + 16777216);   // [B,H,64,S] bf16
  unsigned short* ctx = (unsigned short*)(ws + 25165824);   // [B*S,1024] bf16

  const float kscale = 0.125f * 1.44269504088896340736f;  // 1/sqrt(64) * log2(e)
  GemmJobs gj;
  gj.A[0] = query; gj.W[0] = wq; gj.bias[0] = bq; gj.out[0] = (void*)Qb; gj.scale[0] = 1.0f;   gj.mode[0] = 0;
  gj.A[1] = key_;  gj.W[1] = wk; gj.bias[1] = bk; gj.out[1] = (void*)Kb; gj.scale[1] = kscale; gj.mode[1] = 0;
  gj.A[2] = value; gj.W[2] = wv; gj.bias[2] = bv; gj.out[2] = (void*)Vb; gj.scale[2] = 1.0f;   gj.mode[2] = 1;
  gemm_t<128, 256, true><<<768, 256, 0, stream>>>(gj);   // 3 blocks/CU, fp32 in

  attn_kernel<<<512, 256, 0, stream>>>(Qb, Kb, Vb, ctx);

  GemmJobs oj;
  oj.A[0] = ctx; oj.W[0] = wo; oj.bias[0] = bo; oj.out[0] = d_out; oj.scale[0] = 1.0f; oj.mode[0] = 2;
  oj.A[1] = oj.A[0]; oj.W[1] = oj.W[0]; oj.bias[1] = oj.bias[0]; oj.out[1] = oj.out[0]; oj.scale[1] = 1.0f; oj.mode[1] = 2;
  oj.A[2] = oj.A[0]; oj.W[2] = oj.W[0]; oj.bias[2] = oj.bias[0]; oj.out[2] = oj.out[0]; oj.scale[2] = 1.0f; oj.mode[2] = 2;
  gemm_t<64, 512, false><<<512, 256, 0, stream>>>(oj);   // 2 blocks/CU, bf16 ctx via gll16
}

// Round 6
// 150.379 us; speedup vs baseline: 1.2077x; 1.2077x over previous
//
#include <hip/hip_runtime.h>
#include <stdint.h>

#define SEQ 2048
#define NH  16

typedef __bf16 bf16x8 __attribute__((ext_vector_type(8)));
typedef float  f32x4  __attribute__((ext_vector_type(4)));
typedef float  f32x16 __attribute__((ext_vector_type(16)));
typedef unsigned uint2v __attribute__((ext_vector_type(2)));

#if __has_builtin(__builtin_amdgcn_exp2f)
#define EXP2(x) __builtin_amdgcn_exp2f(x)
#else
#define EXP2(x) exp2f(x)
#endif

#define WAITV0 asm volatile("s_waitcnt vmcnt(0)" ::: "memory")
#define WAITV4 asm volatile("s_waitcnt vmcnt(4)" ::: "memory")
#define SBAR() do { __builtin_amdgcn_sched_barrier(0); __builtin_amdgcn_s_barrier(); __builtin_amdgcn_sched_barrier(0); } while (0)

__device__ __forceinline__ unsigned short f2bf(float f) {
  union { float f; uint32_t u; } v; v.f = f;
  uint32_t r = v.u + 0x7fffu + ((v.u >> 16) & 1u);
  return (unsigned short)(r >> 16);
}

__device__ __forceinline__ void gll16(const void* g, void* l) {
  __builtin_amdgcn_global_load_lds((const __attribute__((address_space(1))) void*)g,
                                   (__attribute__((address_space(3))) void*)l, 16, 0, 0);
}

__device__ __forceinline__ f32x4 mfma16(bf16x8 a, bf16x8 b, f32x4 c) {
  return __builtin_amdgcn_mfma_f32_16x16x32_bf16(a, b, c, 0, 0, 0);
}
__device__ __forceinline__ f32x16 mfma32(bf16x8 a, bf16x8 b, f32x16 c) {
  return __builtin_amdgcn_mfma_f32_32x32x16_bf16(a, b, c, 0, 0, 0);
}

// ---------------- fused fp32 -> bf16 convert (7 jobs, 1 launch) ----------------
struct CvtJobs {
  const float* s[7];
  unsigned short* d[7];
  int n4[7];
};

__global__ void cvt_all(CvtJobs J) {
  int j = blockIdx.y;
  const float* __restrict__ s = J.s[j];
  unsigned short* __restrict__ d = J.d[j];
  int n4 = J.n4[j];
  int st = gridDim.x * blockDim.x;
  for (int i = blockIdx.x * blockDim.x + threadIdx.x; i < n4; i += st) {
    float4 v = ((const float4*)s)[i];
    union { unsigned short u[4]; uint2 q; } o;
    o.u[0] = f2bf(v.x); o.u[1] = f2bf(v.y); o.u[2] = f2bf(v.z); o.u[3] = f2bf(v.w);
    ((uint2*)d)[i] = o.q;
  }
}

// ---------------- GEMM BMx128, BK=64, single-buffered (m97 structure) ----------------
// C[m][n] = (sum_k A[m][k]*W[n][k] + bias[n]) * scale
// mode 0: bf16 [B,H,S,DK]; mode 1: bf16 [B,H,DK,S]; mode 2: fp32 [M][N].
struct GemmJobs {
  const unsigned short* A[3];
  const unsigned short* W[3];
  const float* bias[3];
  void* out[3];
  float scale[3];
  int mode[3];
};

// NB = blocks per job = (4096/BM) * (1024/128)
template<int BM, int NB>
__global__ __launch_bounds__(256, (BM == 128 ? 3 : 2)) void gemm_t(GemmJobs J) {
  __shared__ alignas(16) unsigned short Asm[BM * 64];
  __shared__ alignas(16) unsigned short Bsm[128 * 64];
  constexpr int MFR = BM / 32;    // acc row-frags per wave
  constexpr int MB = 4096 / BM;   // m-blocks per job
  const int tid = threadIdx.x;
  const int l = tid & 63, w = tid >> 6;
  const int wr = w >> 1, wc = w & 1;
  const int lg = l >> 4, lo = l & 15;

  // XCD-aware swizzle (nwg % 8 == 0)
  const int nwg = gridDim.x;
  const int id = blockIdx.x;
  const int swz = (id & 7) * (nwg >> 3) + (id >> 3);
  const int g = swz / NB;
  const int rem = swz % NB;
  const int m0 = (rem % MB) * BM;     // m fastest: consecutive blocks share W panel
  const int n0 = (rem / MB) * 128;

  const unsigned short* __restrict__ A = J.A[g];
  const unsigned short* __restrict__ W = J.W[g];
  const float* __restrict__ bias = J.bias[g];
  const int mode = J.mode[g];
  const float scale = J.scale[g];

  f32x4 acc[MFR][4] = {};

  for (int kt = 0; kt < 16; ++kt) {
    // stage A (BM x 64k) and B (128 x 64k), chunk-swizzled source, linear LDS dest
#pragma unroll
    for (int it = 0; it < BM / 32; ++it) {
      int chunk = it * 256 + tid;
      int row = chunk >> 3, c = chunk & 7;
      const char* src = (const char*)A + (((size_t)(m0 + row) << 10) + (kt << 6)) * 2 + ((c ^ (row & 7)) << 4);
      gll16(src, (char*)Asm + ((it * 256 + (tid & ~63)) << 4));
    }
#pragma unroll
    for (int it = 0; it < 4; ++it) {
      int chunk = it * 256 + tid;
      int row = chunk >> 3, c = chunk & 7;
      const char* src = (const char*)W + (((size_t)(n0 + row) << 10) + (kt << 6)) * 2 + ((c ^ (row & 7)) << 4);
      gll16(src, (char*)Bsm + ((it * 256 + (tid & ~63)) << 4));
    }
    WAITV0;
    SBAR();
#pragma unroll
    for (int kf = 0; kf < 2; ++kf) {
      bf16x8 af[MFR], bfr[4];
#pragma unroll
      for (int mf = 0; mf < MFR; ++mf) {
        int row = wr * (BM / 2) + mf * 16 + lo;
        int pos = (kf * 4 + lg) ^ (row & 7);
        af[mf] = *(const bf16x8*)((const char*)Asm + row * 128 + pos * 16);
      }
#pragma unroll
      for (int nf = 0; nf < 4; ++nf) {
        int row = wc * 64 + nf * 16 + lo;
        int pos = (kf * 4 + lg) ^ (row & 7);
        bfr[nf] = *(const bf16x8*)((const char*)Bsm + row * 128 + pos * 16);
      }
#pragma unroll
      for (int mf = 0; mf < MFR; ++mf)
#pragma unroll
        for (int nf = 0; nf < 4; ++nf)
          acc[mf][nf] = mfma16(af[mf], bfr[nf], acc[mf][nf]);
    }
    SBAR();  // all waves done reading before restage
  }

  // epilogue
#pragma unroll
  for (int mf = 0; mf < MFR; ++mf)
#pragma unroll
    for (int nf = 0; nf < 4; ++nf) {
      int gcol = n0 + wc * 64 + nf * 16 + lo;
      float bv = bias[gcol];
#pragma unroll
      for (int r = 0; r < 4; ++r) {
        int grow = m0 + wr * (BM / 2) + mf * 16 + lg * 4 + r;
        float v = (acc[mf][nf][r] + bv) * scale;
        if (mode == 2) {
          ((float*)J.out[g])[((size_t)grow << 10) + gcol] = v;
        } else {
          int b = grow >> 11, s = grow & 2047, h = gcol >> 6, dk = gcol & 63;
          size_t idx;
          if (mode == 0) idx = ((((size_t)((b << 4) + h) << 11) + s) << 6) + dk;
          else           idx = ((((size_t)((b << 4) + h) << 6) + dk) << 11) + s;
          ((__bf16*)J.out[g])[idx] = (__bf16)v;
        }
      }
    }
}

// ---------------- flash attention: 32x32 MFMA, in-register softmax (T12) -------------
// Qb: [B*H][S][64] bf16. Kb: same, pre-scaled by 0.125*log2(e). Vt: [B*H][64][S] bf16.
// Grid 512 (XCD-swizzled -> bh, qtile), 256 threads = 4 waves x 32 q-rows. KVBLK=64 dbuf.
// Per lane: ql = l&31 (owns softmax of q=ql), hi = l>>5.
// QK^T swapped: sN[reg] = S[kv = N*32 + (reg&3)+8*(reg>>2)+4*hi][q = ql].
__global__ __launch_bounds__(256, 2) void attn_kernel(const unsigned short* __restrict__ Qb,
                                                      const unsigned short* __restrict__ Kb,
                                                      const unsigned short* __restrict__ Vt,
                                                      unsigned short* __restrict__ ctx) {
  __shared__ alignas(16) unsigned short Ksm[2][64 * 64];  // [kv][64dk] swizzled, dbuf (16KB)
  __shared__ alignas(16) unsigned short Vsm[2][64 * 64];  // [dk][64kv] swizzled, dbuf (16KB)
  const int tid = threadIdx.x;
  const int l = tid & 63, w = tid >> 6;   // 4 waves
  const int ql = l & 31, hi = l >> 5;

  // XCD swizzle: 512 blocks -> each XCD owns 4 complete heads
  const int id = blockIdx.x;
  const int swz = (id & 7) * 64 + (id >> 3);
  const int bh = swz >> 4;
  const int qt = swz & 15;

  const unsigned short* Qp = Qb + (size_t)bh * SEQ * 64;
  const unsigned short* Kp = Kb + (size_t)bh * SEQ * 64;
  const unsigned short* Vp = Vt + (size_t)bh * 64 * SEQ;
  const int q0 = qt * 128 + w * 32;

  // Q as B-operand: qb[c] = Q[q0+ql][c*16 + hi*8 .. +7]
  bf16x8 qb[4];
#pragma unroll
  for (int c = 0; c < 4; ++c)
    qb[c] = *(const bf16x8*)((const char*)Qp + (((size_t)(q0 + ql)) << 7) + c * 32 + hi * 16);
  WAITV0;  // Q retired; vmcnt now tracks only staging

  f32x16 o0 = {}, o1 = {};      // O[q(reg)][dk = ql] and [dk = 32+ql]
  float m_ = -1e30f, l_ = 0.f;  // running max/sum for q = ql (dup across hi)

#define ASTAGE(b, t)                                                                      \
  do {                                                                                    \
    const int kv0s = (t) << 6;                                                            \
    _Pragma("unroll")                                                                     \
    for (int it = 0; it < 2; ++it) {                                                      \
      int chunk = it * 256 + tid;                                                         \
      int row = chunk >> 3, c = chunk & 7;                                                \
      const char* ksrc = (const char*)Kp + ((size_t)(kv0s + row) << 7) + ((c ^ (row & 7)) << 4); \
      gll16(ksrc, (char*)Ksm[b] + ((it * 256 + (tid & ~63)) << 4));                       \
      const char* vsrc = (const char*)Vp + ((size_t)row << 12) + (kv0s << 1) + ((c ^ (row & 7)) << 4); \
      gll16(vsrc, (char*)Vsm[b] + ((it * 256 + (tid & ~63)) << 4));                       \
    }                                                                                     \
  } while (0)

  ASTAGE(0, 0);

  for (int t = 0; t < SEQ / 64; ++t) {
    const int cur = t & 1;
    if (t < SEQ / 64 - 1) {
      ASTAGE(cur ^ 1, t + 1);
      WAITV4;          // current tile's 4 loads done; next tile's 4 in flight
    } else {
      WAITV0;
    }
    SBAR();

    // ---- S^T = K Q^T (swapped) ----
    f32x16 s0 = {}, s1 = {};
    __builtin_amdgcn_s_setprio(1);
#pragma unroll
    for (int c = 0; c < 4; ++c) {
      int pr = c * 2 + hi;
      bf16x8 k0 = *(const bf16x8*)((const char*)Ksm[cur] + ql * 128 + ((pr ^ (ql & 7)) << 4));
      bf16x8 k1 = *(const bf16x8*)((const char*)Ksm[cur] + (32 + ql) * 128 + ((pr ^ ((32 + ql) & 7)) << 4));
      s0 = mfma32(k0, qb[c], s0);
      s1 = mfma32(k1, qb[c], s1);
    }
    __builtin_amdgcn_s_setprio(0);

    // ---- online softmax, fully lane-local for q = ql ----
#define MAX4(v, i) fmaxf(fmaxf(v[i], v[i+1]), fmaxf(v[i+2], v[i+3]))
    float mA = fmaxf(fmaxf(MAX4(s0, 0), MAX4(s0, 4)), fmaxf(MAX4(s0, 8), MAX4(s0, 12)));
    float mB = fmaxf(fmaxf(MAX4(s1, 0), MAX4(s1, 4)), fmaxf(MAX4(s1, 8), MAX4(s1, 12)));
    float mx = fmaxf(mA, mB);
    mx = fmaxf(mx, __shfl_xor(mx, 32));
#undef MAX4

    if (__any((int)(mx > m_))) {
      float mnew = fmaxf(m_, mx);
      float fac = EXP2(m_ - mnew);
      m_ = mnew;
#pragma unroll
      for (int r = 0; r < 16; ++r) { s0[r] = EXP2(s0[r] - mnew); s1[r] = EXP2(s1[r] - mnew); }
#define SUM4(v, i) ((v[i] + v[i+1]) + (v[i+2] + v[i+3]))
      float ps = ((SUM4(s0, 0) + SUM4(s0, 4)) + (SUM4(s0, 8) + SUM4(s0, 12)))
               + ((SUM4(s1, 0) + SUM4(s1, 4)) + (SUM4(s1, 8) + SUM4(s1, 12)));
      ps += __shfl_xor(ps, 32);
      l_ = l_ * fac + ps;
      // O-rescale: fac indexed by reg-row q, lives at lane q
#pragma unroll
      for (int reg = 0; reg < 16; ++reg) {
        int qrow = (reg & 3) + 8 * (reg >> 2) + 4 * hi;
        float fb = __shfl(fac, qrow);
        o0[reg] *= fb; o1[reg] *= fb;
      }
    } else {
#pragma unroll
      for (int r = 0; r < 16; ++r) { s0[r] = EXP2(s0[r] - m_); s1[r] = EXP2(s1[r] - m_); }
      float ps = ((SUM4(s0, 0) + SUM4(s0, 4)) + (SUM4(s0, 8) + SUM4(s0, 12)))
               + ((SUM4(s1, 0) + SUM4(s1, 4)) + (SUM4(s1, 8) + SUM4(s1, 12)));
      ps += __shfl_xor(ps, 32);
      l_ += ps;
#undef SUM4
    }

    // ---- P -> A-operand in registers: cvt_pk + permlane32_swap (no LDS) ----
    // pa[c] elem j = P[q=ql][kv = c*16 + hi*8 + j]
    bf16x8 pa[4];
#pragma unroll
    for (int c = 0; c < 4; ++c) {
      const int rb = (c & 1) * 8;
      float e0, e1, e2, e3, e4, e5, e6, e7;
      if ((c >> 1) == 0) { e0=s0[rb]; e1=s0[rb+1]; e2=s0[rb+2]; e3=s0[rb+3]; e4=s0[rb+4]; e5=s0[rb+5]; e6=s0[rb+6]; e7=s0[rb+7]; }
      else               { e0=s1[rb]; e1=s1[rb+1]; e2=s1[rb+2]; e3=s1[rb+3]; e4=s1[rb+4]; e5=s1[rb+5]; e6=s1[rb+6]; e7=s1[rb+7]; }
      unsigned X0, X1, Z0, Z1;
      asm("v_cvt_pk_bf16_f32 %0, %1, %2" : "=v"(X0) : "v"(e0), "v"(e1));
      asm("v_cvt_pk_bf16_f32 %0, %1, %2" : "=v"(X1) : "v"(e2), "v"(e3));
      asm("v_cvt_pk_bf16_f32 %0, %1, %2" : "=v"(Z0) : "v"(e4), "v"(e5));
      asm("v_cvt_pk_bf16_f32 %0, %1, %2" : "=v"(Z1) : "v"(e6), "v"(e7));
      uint2v rA = __builtin_amdgcn_permlane32_swap(X0, Z0, false, false);
      uint2v rB = __builtin_amdgcn_permlane32_swap(X1, Z1, false, false);
      union { unsigned u[4]; bf16x8 v; } pk_;
      pk_.u[0] = rA[0]; pk_.u[1] = rB[0]; pk_.u[2] = rA[1]; pk_.u[3] = rB[1];
      pa[c] = pk_.v;
    }

    // ---- O += P V ----
    __builtin_amdgcn_s_setprio(1);
#pragma unroll
    for (int c = 0; c < 4; ++c) {
      int pr = c * 2 + hi;
      bf16x8 v0 = *(const bf16x8*)((const char*)Vsm[cur] + ql * 128 + ((pr ^ (ql & 7)) << 4));
      bf16x8 v1 = *(const bf16x8*)((const char*)Vsm[cur] + (32 + ql) * 128 + ((pr ^ ((32 + ql) & 7)) << 4));
      o0 = mfma32(pa[c], v0, o0);
      o1 = mfma32(pa[c], v1, o1);
    }
    __builtin_amdgcn_s_setprio(0);
    SBAR();  // all waves done reading buf[cur] before restage
  }
#undef ASTAGE

  // ---- epilogue: normalize, store ctx [B*S][1024] ----
  const int b = bh >> 4, h = bh & 15;
#pragma unroll
  for (int reg = 0; reg < 16; ++reg) {
    int qrow = (reg & 3) + 8 * (reg >> 2) + 4 * hi;
    float lr = __shfl(l_, qrow);
    float inv = 1.f / lr;
    int srow = q0 + qrow;
    size_t off = (((size_t)(b * SEQ + srow)) << 10) + h * 64 + ql;
    ((__bf16*)ctx)[off]      = (__bf16)(o0[reg] * inv);
    ((__bf16*)ctx)[off + 32] = (__bf16)(o1[reg] * inv);
  }
}

// ---------------- launch ----------------
extern "C" void kernel_launch(void* const* d_in, const int* in_sizes, int n_in,
                              void* d_out, int out_size, void* d_ws, size_t ws_size,
                              hipStream_t stream) {
  const float* query = (const float*)d_in[0];
  const float* key_  = (const float*)d_in[1];
  const float* value = (const float*)d_in[2];
  const float* wq = (const float*)d_in[4];
  const float* bq = (const float*)d_in[5];
  const float* wk = (const float*)d_in[6];
  const float* bk = (const float*)d_in[7];
  const float* wv = (const float*)d_in[8];
  const float* bv = (const float*)d_in[9];
  const float* wo = (const float*)d_in[10];
  const float* bo = (const float*)d_in[11];

  char* ws = (char*)d_ws;
  unsigned short* xq  = (unsigned short*)(ws + 0);
  unsigned short* xk  = (unsigned short*)(ws + 8388608);
  unsigned short* xv  = (unsigned short*)(ws + 16777216);
  unsigned short* wqb = (unsigned short*)(ws + 25165824);
  unsigned short* wkb = (unsigned short*)(ws + 27262976);
  unsigned short* wvb = (unsigned short*)(ws + 29360128);
  unsigned short* wob = (unsigned short*)(ws + 31457280);
  unsigned short* Qb  = (unsigned short*)(ws + 33554432);   // [B,H,S,64]
  unsigned short* Kb  = (unsigned short*)(ws + 41943040);   // [B,H,S,64] (pre-scaled, log2e folded)
  unsigned short* Vb  = (unsigned short*)(ws + 50331648);   // [B,H,64,S]
  unsigned short* ctx = (unsigned short*)(ws + 58720256);   // [B*S,1024]

  CvtJobs cj;
  cj.s[0] = query; cj.d[0] = xq;  cj.n4[0] = 1048576;
  cj.s[1] = key_;  cj.d[1] = xk;  cj.n4[1] = 1048576;
  cj.s[2] = value; cj.d[2] = xv;  cj.n4[2] = 1048576;
  cj.s[3] = wq;    cj.d[3] = wqb; cj.n4[3] = 262144;
  cj.s[4] = wk;    cj.d[4] = wkb; cj.n4[4] = 262144;
  cj.s[5] = wv;    cj.d[5] = wvb; cj.n4[5] = 262144;
  cj.s[6] = wo;    cj.d[6] = wob; cj.n4[6] = 262144;
  cvt_all<<<dim3(256, 7), 256, 0, stream>>>(cj);

  const float kscale = 0.125f * 1.44269504088896340736f;  // 1/sqrt(64) * log2(e)
  GemmJobs gj;
  gj.A[0] = xq; gj.W[0] = wqb; gj.bias[0] = bq; gj.out[0] = (void*)Qb; gj.scale[0] = 1.0f;   gj.mode[0] = 0;
  gj.A[1] = xk; gj.W[1] = wkb; gj.bias[1] = bk; gj.out[1] = (void*)Kb; gj.scale[1] = kscale; gj.mode[1] = 0;
  gj.A[2] = xv; gj.W[2] = wvb; gj.bias[2] = bv; gj.out[2] = (void*)Vb; gj.scale[2] = 1.0f;   gj.mode[2] = 1;
  gemm_t<128, 256><<<768, 256, 0, stream>>>(gj);   // 3 blocks/CU, balanced

  attn_kernel<<<512, 256, 0, stream>>>(Qb, Kb, Vb, ctx);

  GemmJobs oj;
  oj.A[0] = ctx; oj.W[0] = wob; oj.bias[0] = bo; oj.out[0] = d_out; oj.scale[0] = 1.0f; oj.mode[0] = 2;
  oj.A[1] = oj.A[0]; oj.W[1] = oj.W[0]; oj.bias[1] = oj.bias[0]; oj.out[1] = oj.out[0]; oj.scale[1] = 1.0f; oj.mode[1] = 2;
  oj.A[2] = oj.A[0]; oj.W[2] = oj.W[0]; oj.bias[2] = oj.bias[0]; oj.out[2] = oj.out[0]; oj.scale[2] = 1.0f; oj.mode[2] = 2;
  gemm_t<64, 512><<<512, 256, 0, stream>>>(oj);    // 2 blocks/CU, balanced
}